// Round 8
// baseline (324.279 us; speedup 1.0000x reference)
//
#include <hip/hip_runtime.h>

#define B_ 4
#define S_ 4096
#define E_ 2048
#define H_ 128

using f32x4 = __attribute__((ext_vector_type(4))) float;
using s16x8 = __attribute__((ext_vector_type(8))) short;
using s16x4 = __attribute__((ext_vector_type(4))) short;

// fp32 -> bf16 bits, round-to-nearest-even
__device__ __forceinline__ short f2bf(float f) {
  unsigned u = __float_as_uint(f);
  u += 0x7FFFu + ((u >> 16) & 1u);
  return (short)(u >> 16);
}

// async global(16B/lane, per-lane addr) -> LDS (wave-uniform base + lane*16)
__device__ __forceinline__ void gload_lds16(const void* g, void* l) {
  __builtin_amdgcn_global_load_lds(
      (const __attribute__((address_space(1))) void*)g,
      (__attribute__((address_space(3))) void*)l, 16, 0, 0);
}

// K=16 bf16 MFMA: D(16q x 16h) = A(16q x 16k) * B(16k x 16h) + C
__device__ __forceinline__ f32x4 mfma16x16x16(s16x4 a, s16x4 b, f32x4 c) {
#if __has_builtin(__builtin_amdgcn_mfma_f32_16x16x16bf16_1k)
  return __builtin_amdgcn_mfma_f32_16x16x16bf16_1k(a, b, c, 0, 0, 0);
#elif __has_builtin(__builtin_amdgcn_mfma_f32_16x16x16_bf16)
  return __builtin_amdgcn_mfma_f32_16x16x16_bf16(a, b, c, 0, 0, 0);
#else
  f32x4 d;
  asm("v_mfma_f32_16x16x16_bf16 %0, %1, %2, %3"
      : "=v"(d) : "v"(a), "v"(b), "v"(c));
  return d;
#endif
}

// ---------------------------------------------------------------------------
// Kernel 1: W (E x H fp32) x3 -> Wt2 K-panel layout, bf16.
// R14 layout: Wt2[((e0>>6)*384 + col)*64 + (e0&63) + c] — i.e. [kb][col][64k]
// panels: for k-block kb, the 384x64 panel is CONTIGUOUS (24 KB per N-half),
// so qkv_gemm can stage it with dense global_load_lds (1 KB per wave-instr).
// ---------------------------------------------------------------------------
__global__ __launch_bounds__(256) void prep_weights(
    const float* __restrict__ Wq, const float* __restrict__ Wk,
    const float* __restrict__ Wv, short* __restrict__ Wt) {
  __shared__ float T[32 * 33];
  int p = blockIdx.y;
  const float* W = (p == 0) ? Wq : ((p == 1) ? Wk : Wv);
  int e0 = (blockIdx.x & 63) * 32;
  int h0 = (blockIdx.x >> 6) * 32;
  int r = threadIdx.x >> 5;
  int c = threadIdx.x & 31;
#pragma unroll
  for (int i = 0; i < 4; ++i) {
    int e = r + 8 * i;
    T[c * 33 + e] = W[(size_t)(e0 + e) * H_ + h0 + c];
  }
  __syncthreads();
  const int kb = e0 >> 6;
  const int kq = e0 & 32;  // e0 is 32-aligned: offset 0 or 32 within panel
#pragma unroll
  for (int i = 0; i < 4; ++i) {
    int h = r + 8 * i;
    int col = p * H_ + h0 + h;
    Wt[((size_t)kb * 384 + col) * 64 + kq + c] = f2bf(T[h * 33 + c]);
  }
}

// ---------------------------------------------------------------------------
// Kernel 2: fused QKV projection GEMM — R14 rebuild (m93/m97 pattern).
// R13 counters: 103us, MfmaUtil 10%, FETCH 135MB (x read once: streaming
// already ideal), HBM 18%: structure-bound. Old 32x192 tile = 48 MFMA per
// 28KB staged/iter, W panel re-staged per 32 x-rows (805MB DS writes total),
// 2 barriers/iter.
// New: 64x192 tile (W staging amortized 2x; 96 MFMA/iter/block), grid 512 =
// 2 blocks/CU co-resident (R13-validated lever), ONE barrier/iter:
//   barrier -> STAGE_W(next, async gload_lds) + issue x loads
//           -> compute(cur) -> convert/write xa(next)
// W staged direct global->LDS from the contiguous Wt2 panel with
// pre-swizzled source (m173) + XOR'd reads ((col&7)<<4), killing the
// 128B-stride bank conflict. x staged via regs (needs fp32->bf16).
// ---------------------------------------------------------------------------
__global__ __launch_bounds__(256) void qkv_gemm(
    const float* __restrict__ x, const short* __restrict__ Wt,
    const float* __restrict__ bq, const float* __restrict__ bk,
    const float* __restrict__ bv,
    short* __restrict__ Q, short* __restrict__ K, short* __restrict__ Vt) {
  __shared__ __attribute__((aligned(16))) short xa[2][64 * 72];   // 18.4 KB
  __shared__ __attribute__((aligned(16))) short wb[2][192 * 64];  // 48 KB

  const int tid = threadIdx.x;
  const int wave = tid >> 6;
  const int lane = tid & 63;
  const int l15 = lane & 15;
  const int quad = lane >> 4;
  const int bid = (int)blockIdx.x;
  const int row0 = (bid >> 1) * 64;
  const int nc0 = (bid & 1) * 192;

  // x staging: thread -> (row sr, 16-col group cg)
  const int sr = tid >> 2;
  const int cg = (tid & 3) * 16;
  const float* xp = x + (size_t)(row0 + sr) * E_ + cg;

  // W staging lane decomposition (8 cols x 8 slots per wave-instr)
  const int wl8 = lane >> 3;  // col within 8-col group
  const int l7 = lane & 7;    // 16B slot within col

  f32x4 acc[4][3];
#pragma unroll
  for (int mg = 0; mg < 4; ++mg)
#pragma unroll
    for (int nt = 0; nt < 3; ++nt) acc[mg][nt] = (f32x4){0.f, 0.f, 0.f, 0.f};

  // async W panel stage: 24 KB (192 cols x 64k), 6 instrs/wave, dense source
  auto STAGE_W = [&](int sel, int it) {
    const char* pan = (const char*)(Wt + ((size_t)it * 384 + nc0) * 64);
    char* dst = (char*)&wb[sel][0] + (size_t)(wave * 48) * 128;
#pragma unroll
    for (int j2 = 0; j2 < 6; ++j2) {
      int col = wave * 48 + j2 * 8 + wl8;
      const char* src = pan + (size_t)col * 128 + ((l7 * 16) ^ ((col & 7) << 4));
      gload_lds16(src, dst + j2 * 1024);
    }
  };
  // x tile -> LDS (bf16), 2 b128 writes/thread
  auto WRITE_X = [&](int sel, const float4* xv) {
    s16x8 a, b2;
    a[0] = f2bf(xv[0].x); a[1] = f2bf(xv[0].y); a[2] = f2bf(xv[0].z); a[3] = f2bf(xv[0].w);
    a[4] = f2bf(xv[1].x); a[5] = f2bf(xv[1].y); a[6] = f2bf(xv[1].z); a[7] = f2bf(xv[1].w);
    b2[0] = f2bf(xv[2].x); b2[1] = f2bf(xv[2].y); b2[2] = f2bf(xv[2].z); b2[3] = f2bf(xv[2].w);
    b2[4] = f2bf(xv[3].x); b2[5] = f2bf(xv[3].y); b2[6] = f2bf(xv[3].z); b2[7] = f2bf(xv[3].w);
    *(s16x8*)&xa[sel][sr * 72 + cg] = a;
    *(s16x8*)&xa[sel][sr * 72 + cg + 8] = b2;
  };

  // prologue: stage k-step 0
  float4 xf[4];
#pragma unroll
  for (int j = 0; j < 4; ++j) xf[j] = *(const float4*)(xp + j * 4);
  STAGE_W(0, 0);
  WRITE_X(0, xf);

  int cur = 0;
  for (int it = 0; it < 32; ++it) {
    __syncthreads();  // buf[cur] ready: W vmcnt drained + xa writes visible
    if (it + 1 < 32) {
      STAGE_W(cur ^ 1, it + 1);  // async during compute
      const float* xpn = xp + (it + 1) * 64;
#pragma unroll
      for (int j = 0; j < 4; ++j) xf[j] = *(const float4*)(xpn + j * 4);
    }

#pragma unroll
    for (int kc = 0; kc < 2; ++kc) {
      const int ko = kc * 32 + quad * 8;
      s16x8 af[4], bfr[3];
#pragma unroll
      for (int mg = 0; mg < 4; ++mg)
        af[mg] = *(const s16x8*)&xa[cur][(mg * 16 + l15) * 72 + ko];
#pragma unroll
      for (int nt = 0; nt < 3; ++nt) {
        int col = wave * 48 + nt * 16 + l15;
        bfr[nt] = *(const s16x8*)((const char*)&wb[cur][0] + (size_t)col * 128 +
                                  ((kc * 64 + quad * 16) ^ ((col & 7) << 4)));
      }
#pragma unroll
      for (int mg = 0; mg < 4; ++mg)
#pragma unroll
        for (int nt = 0; nt < 3; ++nt)
          acc[mg][nt] = __builtin_amdgcn_mfma_f32_16x16x32_bf16(
              af[mg], bfr[nt], acc[mg][nt], 0, 0, 0);
    }

    if (it + 1 < 32) WRITE_X(cur ^ 1, xf);  // readers of xa[cur^1] done pre-barrier
    cur ^= 1;
  }

  const float scale = 0.08838834764831845f;  // 1/sqrt(128), folded into Q
  const int b = row0 >> 12;
  const int s_base = row0 & (S_ - 1);
#pragma unroll
  for (int nt = 0; nt < 3; ++nt) {
    int col = nc0 + wave * 48 + nt * 16 + l15;
    int p = col >> 7;
    int h = col & (H_ - 1);
    if (p == 2) {
      float bsv = bv[h];
#pragma unroll
      for (int mg = 0; mg < 4; ++mg) {
        int s0 = s_base + mg * 16 + quad * 4;
        s16x4 vv;
#pragma unroll
        for (int r = 0; r < 4; ++r) vv[r] = f2bf(acc[mg][nt][r] + bsv);
        *(s16x4*)&Vt[((size_t)b * H_ + h) * S_ + s0] = vv;
      }
    } else if (p == 0) {
      float bsv = bq[h];
#pragma unroll
      for (int mg = 0; mg < 4; ++mg)
#pragma unroll
        for (int r = 0; r < 4; ++r) {
          int row = row0 + mg * 16 + quad * 4 + r;
          Q[(size_t)row * H_ + h] = f2bf((acc[mg][nt][r] + bsv) * scale);
        }
    } else {
      float bsv = bk[h];
#pragma unroll
      for (int mg = 0; mg < 4; ++mg)
#pragma unroll
        for (int r = 0; r < 4; ++r) {
          int row = row0 + mg * 16 + quad * 4 + r;
          K[(size_t)row * H_ + h] = f2bf(acc[mg][nt][r] + bsv);
        }
    }
  }
}

// ---------------------------------------------------------------------------
// Kernel 3: causal flash attention — R13 (unchanged; split-K + 2 blocks/CU).
// ---------------------------------------------------------------------------
__global__ __launch_bounds__(512) void flash_attn(
    const short* __restrict__ Qb, const short* __restrict__ Kb,
    const short* __restrict__ Vtb, float* __restrict__ O0,
    float* __restrict__ O1, float* __restrict__ ML) {
  __shared__ __attribute__((aligned(16))) short KT[2][64 * 128];  // 2x16KB
  __shared__ __attribute__((aligned(16))) short VT[2][128 * 64];  // 2x16KB
  __shared__ float mx[2][8][16];                                  // 1KB
  __shared__ float lx[8][16];                                     // 512B

  const int tid = threadIdx.x;
  const int w = tid >> 6;
  const int lane = tid & 63;
  const int l15 = lane & 15;
  const int quad = lane >> 4;
  const int rg = w & 3;        // row-group: rows 16*rg .. 16*rg+15
  const int kh = w >> 2;       // key-half within tile: keys kh*32 ..
  const int bid = (int)blockIdx.x;
  const int half = bid & 1;    // split-K half
  const int slot = bid >> 1;
  const int b = slot & 3;
  const int T = 63 - (slot >> 2);  // heavy q-tiles first
  const int q0 = T * 64;
  const int nk = T + 1;
  const int hsplit = (nk + 1) >> 1;
  const int i0 = half ? hsplit : 0;
  const int i1 = half ? nk : hsplit;
  const size_t bo = (size_t)b * S_ * H_;
  const short* Kg = Kb + bo;                    // [s][h], 256B rows
  const short* Vg = Vtb + (size_t)b * H_ * S_;  // [h][s], 8192B rows
  const float L2E = 1.4426950408889634f;

  auto STAGE = [&](int sel, int kb) {
    const char* kgp = (const char*)Kg + (size_t)kb * 256;
    const char* vgp = (const char*)Vg + (size_t)kb * 2;
    char* kl = (char*)&KT[sel][0] + (8 * w) * 256;
    char* vl = (char*)&VT[sel][0] + (16 * w) * 128;
#pragma unroll
    for (int j = 0; j < 2; ++j) {
      int krow = 8 * w + 4 * j + (lane >> 4);
      int kcol = ((lane & 15) << 4) ^ ((((lane >> 4) + 4 * j) & 7) << 4);
      gload_lds16(kgp + (size_t)krow * 256 + kcol, kl + j * 1024);
      int vrow = 16 * w + 8 * j + (lane >> 3);
      int vcol = ((lane & 7) << 4) ^ (((lane >> 3) & 7) << 4);
      gload_lds16(vgp + (size_t)vrow * 8192 + vcol, vl + j * 1024);
    }
  };

  s16x8 aq[4];
#pragma unroll
  for (int kt = 0; kt < 4; ++kt)
    aq[kt] = *(const s16x8*)(Qb + bo + (size_t)(q0 + 16 * rg + l15) * H_ +
                             kt * 32 + quad * 8);

  f32x4 oacc[8];
#pragma unroll
  for (int nt = 0; nt < 8; ++nt) oacc[nt] = (f32x4){0.f, 0.f, 0.f, 0.f};
  float m15 = -3.0e38f;
  float mT[4];
  float l15acc = 0.f;
#pragma unroll
  for (int r = 0; r < 4; ++r) mT[r] = -3.0e38f;

  const int swr = (l15 & 7) << 4;
  const int q4 = quad * 4;

  int cur = 0;
  if (i0 < i1) STAGE(0, i0 * 64);
  for (int i = i0; i < i1; ++i) {
    __syncthreads();
    if (i + 1 < i1) STAGE(cur ^ 1, (i + 1) * 64);

    const char* Kl = (const char*)&KT[cur][0];
    const char* Vl = (const char*)&VT[cur][0];

    f32x4 sc[2];
#pragma unroll
    for (int nt = 0; nt < 2; ++nt) {
      f32x4 a = (f32x4){0.f, 0.f, 0.f, 0.f};
      const int krow = kh * 32 + nt * 16 + l15;
#pragma unroll
      for (int kt = 0; kt < 4; ++kt) {
        const s16x8 kf = *(const s16x8*)(Kl + krow * 256 +
                                         ((kt * 64 + quad * 16) ^ swr));
        a = __builtin_amdgcn_mfma_f32_16x16x32_bf16(kf, aq[kt], a, 0, 0, 0);
      }
      sc[nt] = a;
    }

    if (i == nk - 1) {
      const int qrow = 16 * rg + l15;
#pragma unroll
      for (int nt = 0; nt < 2; ++nt)
#pragma unroll
        for (int r = 0; r < 4; ++r)
          if (kh * 32 + nt * 16 + q4 + r > qrow) sc[nt][r] = -3.0e38f;
    }

    float vm = fmaxf(fmaxf(fmaxf(sc[0][0], sc[0][1]), fmaxf(sc[0][2], sc[0][3])),
                     fmaxf(fmaxf(sc[1][0], sc[1][1]), fmaxf(sc[1][2], sc[1][3])));
    vm = fmaxf(vm, __shfl_xor(vm, 16));
    vm = fmaxf(vm, __shfl_xor(vm, 32));
    const int par = i & 1;
    if (lane < 16) mx[par][w][lane] = vm;
    __asm__ volatile("s_waitcnt lgkmcnt(0)" ::: "memory");
    __asm__ volatile("s_barrier" ::: "memory");

    float tile_m = fmaxf(vm, mx[par][w ^ 4][l15]);
    float mn = fmaxf(m15, tile_m);
    float al15 = exp2f((m15 - mn) * L2E);
    m15 = mn;
    float alT[4];
#pragma unroll
    for (int r = 0; r < 4; ++r) {
      float a2 = fmaxf(mx[par][w][q4 + r], mx[par][w ^ 4][q4 + r]);
      float mnT = fmaxf(mT[r], a2);
      alT[r] = exp2f((mT[r] - mnT) * L2E);
      mT[r] = mnT;
    }

    s16x4 ap[2];
    float lpart = 0.f;
#pragma unroll
    for (int nt = 0; nt < 2; ++nt)
#pragma unroll
      for (int r = 0; r < 4; ++r) {
        float pv = exp2f((sc[nt][r] - m15) * L2E);
        lpart += pv;
        ap[nt][r] = f2bf(pv);
      }
    l15acc = l15acc * al15 + lpart;

#pragma unroll
    for (int ht = 0; ht < 8; ++ht)
#pragma unroll
      for (int r = 0; r < 4; ++r) oacc[ht][r] *= alT[r];

#pragma unroll
    for (int ht = 0; ht < 8; ++ht) {
#pragma unroll
      for (int nt = 0; nt < 2; ++nt) {
        const s16x4 vf = *(const s16x4*)(Vl + (ht * 16 + l15) * 128 +
                                         ((kh * 64 + nt * 32 + quad * 8) ^ swr));
        oacc[ht] = mfma16x16x16(ap[nt], vf, oacc[ht]);
      }
    }

    cur ^= 1;
  }

  float lw = l15acc;
  lw += __shfl_xor(lw, 16);
  lw += __shfl_xor(lw, 32);
  if (lane < 16) lx[w][lane] = lw;
  __syncthreads();

  float* Ob = (float*)&KT[0][0];
  if (kh == 1) {
#pragma unroll
    for (int ht = 0; ht < 8; ++ht)
#pragma unroll
      for (int r = 0; r < 4; ++r)
        Ob[rg * 2048 + (q4 + r) * 128 + ht * 16 + l15] = oacc[ht][r];
  }
  __syncthreads();
  if (kh == 0) {
    float* Od = half ? O1 : O0;
    if (l15 == 0) {
#pragma unroll
      for (int r = 0; r < 4; ++r) {
        int row = q0 + 16 * rg + q4 + r;
        float* mlp = ML + ((size_t)half * (B_ * S_) + b * S_ + row) * 2;
        mlp[0] = mT[r];
        mlp[1] = lx[w][q4 + r] + lx[w ^ 4][q4 + r];
      }
    }
#pragma unroll
    for (int ht = 0; ht < 8; ++ht)
#pragma unroll
      for (int r = 0; r < 4; ++r) {
        float o = oacc[ht][r] + Ob[rg * 2048 + (q4 + r) * 128 + ht * 16 + l15];
        Od[bo + (size_t)(q0 + 16 * rg + q4 + r) * H_ + ht * 16 + l15] = o;
      }
  }
}

// ---------------------------------------------------------------------------
// Kernel 4: merge the two split-K halves (unchanged).
// ---------------------------------------------------------------------------
__global__ __launch_bounds__(256) void merge_halves(
    float* __restrict__ O0, const float* __restrict__ O1,
    const float* __restrict__ ML) {
  const float L2E = 1.4426950408889634f;
  const int total = B_ * S_ * H_;
  int idx = (int)blockIdx.x * 256 + (int)threadIdx.x;
  for (; idx < total; idx += (int)gridDim.x * 256) {
    int brow = idx >> 7;  // b*S + s
    float m1 = ML[(size_t)brow * 2];
    float l1 = ML[(size_t)brow * 2 + 1];
    float m2 = ML[((size_t)(B_ * S_) + brow) * 2];
    float l2 = ML[((size_t)(B_ * S_) + brow) * 2 + 1];
    float M = fmaxf(m1, m2);
    float e1 = exp2f((m1 - M) * L2E);
    float e2 = exp2f((m2 - M) * L2E);
    float denom = e1 * l1 + e2 * l2;
    O0[idx] = (e1 * O0[idx] + e2 * O1[idx]) / denom;
  }
}

// ---------------------------------------------------------------------------
extern "C" void kernel_launch(void* const* d_in, const int* in_sizes, int n_in,
                              void* d_out, int out_size, void* d_ws, size_t ws_size,
                              hipStream_t stream) {
  const float* x  = (const float*)d_in[0];
  const float* Wq = (const float*)d_in[1];
  const float* bq = (const float*)d_in[2];
  const float* Wk = (const float*)d_in[3];
  const float* bk = (const float*)d_in[4];
  const float* Wv = (const float*)d_in[5];
  const float* bv = (const float*)d_in[6];

  // ws: Wt(1.5MB) | Q | K | Vt (4.2MB each, bf16) | O1 (8.4MB f32) | ML (256KB)
  short* Wt = (short*)d_ws;
  short* Q  = Wt + (size_t)384 * E_;
  short* K  = Q + (size_t)B_ * S_ * H_;
  short* Vt = K + (size_t)B_ * S_ * H_;
  float* O1 = (float*)(Vt + (size_t)B_ * S_ * H_);
  float* ML = O1 + (size_t)B_ * S_ * H_;
  float* out = (float*)d_out;

  hipLaunchKernelGGL(prep_weights, dim3(64 * 4, 3), dim3(256), 0, stream,
                     Wq, Wk, Wv, Wt);
  // 512 blocks = 256 row-tiles (64 rows) x 2 N-halves; 2 blocks/CU
  hipLaunchKernelGGL(qkv_gemm, dim3((B_ * S_) / 64 * 2), dim3(256), 0, stream,
                     x, Wt, bq, bk, bv, Q, K, Vt);
  // 512 blocks = 64 q-tiles x 4 batches x 2 split-K halves, 2 blocks/CU
  hipLaunchKernelGGL(flash_attn, dim3(64 * B_ * 2), dim3(512), 0, stream,
                     Q, K, Vt, out, O1, ML);
  hipLaunchKernelGGL(merge_halves, dim3(2048), dim3(256), 0, stream,
                     out, O1, ML);
}

// Round 9
// 308.545 us; speedup vs baseline: 1.0510x; 1.0510x over previous
//
#include <hip/hip_runtime.h>

#define B_ 4
#define S_ 4096
#define E_ 2048
#define H_ 128

using f32x4 = __attribute__((ext_vector_type(4))) float;
using s16x8 = __attribute__((ext_vector_type(8))) short;
using s16x4 = __attribute__((ext_vector_type(4))) short;

// fp32 -> bf16 bits, round-to-nearest-even
__device__ __forceinline__ short f2bf(float f) {
  unsigned u = __float_as_uint(f);
  u += 0x7FFFu + ((u >> 16) & 1u);
  return (short)(u >> 16);
}

// async global(16B/lane, per-lane addr) -> LDS (wave-uniform base + lane*16)
__device__ __forceinline__ void gload_lds16(const void* g, void* l) {
  __builtin_amdgcn_global_load_lds(
      (const __attribute__((address_space(1))) void*)g,
      (__attribute__((address_space(3))) void*)l, 16, 0, 0);
}

// K=16 bf16 MFMA: D(16q x 16h) = A(16q x 16k) * B(16k x 16h) + C
__device__ __forceinline__ f32x4 mfma16x16x16(s16x4 a, s16x4 b, f32x4 c) {
#if __has_builtin(__builtin_amdgcn_mfma_f32_16x16x16bf16_1k)
  return __builtin_amdgcn_mfma_f32_16x16x16bf16_1k(a, b, c, 0, 0, 0);
#elif __has_builtin(__builtin_amdgcn_mfma_f32_16x16x16_bf16)
  return __builtin_amdgcn_mfma_f32_16x16x16_bf16(a, b, c, 0, 0, 0);
#else
  f32x4 d;
  asm("v_mfma_f32_16x16x16_bf16 %0, %1, %2, %3"
      : "=v"(d) : "v"(a), "v"(b), "v"(c));
  return d;
#endif
}

// ---------------------------------------------------------------------------
// Kernel 1: W (E x H fp32) x3 -> Wt K-panel layout [kb][col][64k], bf16.
// Panel for k-block kb is contiguous (24 KB per 192-col N-half) so qkv_gemm
// stages it with dense global_load_lds (1 KB per wave-instruction).
// ---------------------------------------------------------------------------
__global__ __launch_bounds__(256) void prep_weights(
    const float* __restrict__ Wq, const float* __restrict__ Wk,
    const float* __restrict__ Wv, short* __restrict__ Wt) {
  __shared__ float T[32 * 33];
  int p = blockIdx.y;
  const float* W = (p == 0) ? Wq : ((p == 1) ? Wk : Wv);
  int e0 = (blockIdx.x & 63) * 32;
  int h0 = (blockIdx.x >> 6) * 32;
  int r = threadIdx.x >> 5;
  int c = threadIdx.x & 31;
#pragma unroll
  for (int i = 0; i < 4; ++i) {
    int e = r + 8 * i;
    T[c * 33 + e] = W[(size_t)(e0 + e) * H_ + h0 + c];
  }
  __syncthreads();
  const int kb = e0 >> 6;
  const int kq = e0 & 32;  // e0 is 32-aligned: offset 0 or 32 within panel
#pragma unroll
  for (int i = 0; i < 4; ++i) {
    int h = r + 8 * i;
    int col = p * H_ + h0 + h;
    Wt[((size_t)kb * 384 + col) * 64 + kq + c] = f2bf(T[h * 33 + c]);
  }
}

// ---------------------------------------------------------------------------
// Kernel 2: fused QKV projection GEMM — R15: R14 structure, 8 WAVES.
// R14 post-mortem: staging rebuild (conflicts 5.2M->2.1M, 1 barrier/iter,
// dense gload_lds W) bought ZERO time -> staging was not binding. The
// binding constraint (same as flash pre-R13) is TLP: 2 waves/SIMD cannot
// cover the ~1000cy x-HBM latency + barrier drains (wall 3800cy/iter vs
// ~1900cy pipe work). R13 proved the fix: more waves at constant structure.
// R15: 512 thr / 8 waves, wave (wm,wn) = rows wm*32+{0,16}, cols wn*48.
// Per-wave work halves; LDS unchanged 67.5KB -> still 2 blocks/CU -> waves
// per CU 8 -> 16 (2->4 per SIMD). Tile/swizzle/barrier scheme identical.
// ---------------------------------------------------------------------------
__global__ __launch_bounds__(512) void qkv_gemm(
    const float* __restrict__ x, const short* __restrict__ Wt,
    const float* __restrict__ bq, const float* __restrict__ bk,
    const float* __restrict__ bv,
    short* __restrict__ Q, short* __restrict__ K, short* __restrict__ Vt) {
  __shared__ __attribute__((aligned(16))) short xa[2][64 * 72];   // 18.4 KB
  __shared__ __attribute__((aligned(16))) short wb[2][192 * 64];  // 48 KB

  const int tid = threadIdx.x;
  const int wave = tid >> 6;
  const int lane = tid & 63;
  const int l15 = lane & 15;
  const int quad = lane >> 4;
  const int wm = wave >> 2;   // row half: rows wm*32 .. wm*32+31
  const int wn = wave & 3;    // col quarter: cols wn*48 .. wn*48+47
  const int bid = (int)blockIdx.x;
  const int row0 = (bid >> 1) * 64;
  const int nc0 = (bid & 1) * 192;

  // x staging: thread -> (row sr, 8-float group); 1 b128 LDS write/thread
  const int sr = tid >> 3;
  const int cg8 = (tid & 7) * 8;
  const float* xp = x + (size_t)(row0 + sr) * E_ + cg8;

  // W staging lane decomposition (8 cols x 8 slots per wave-instr)
  const int wl8 = lane >> 3;  // col within 8-col group
  const int l7 = lane & 7;    // 16B slot within col

  f32x4 acc[2][3];
#pragma unroll
  for (int mg = 0; mg < 2; ++mg)
#pragma unroll
    for (int nt = 0; nt < 3; ++nt) acc[mg][nt] = (f32x4){0.f, 0.f, 0.f, 0.f};

  // async W panel stage: 24 KB (192 cols x 64k), 3 instrs per wave
  auto STAGE_W = [&](int sel, int it) {
    const char* pan = (const char*)(Wt + ((size_t)it * 384 + nc0) * 64);
    char* dst = (char*)&wb[sel][0] + (size_t)(wave * 24) * 128;
#pragma unroll
    for (int j2 = 0; j2 < 3; ++j2) {
      int col = wave * 24 + j2 * 8 + wl8;
      const char* src = pan + (size_t)col * 128 + ((l7 * 16) ^ ((col & 7) << 4));
      gload_lds16(src, dst + j2 * 1024);
    }
  };
  // x tile -> LDS (bf16), 1 b128 write/thread
  auto WRITE_X = [&](int sel, const float4* xv) {
    s16x8 a;
    a[0] = f2bf(xv[0].x); a[1] = f2bf(xv[0].y); a[2] = f2bf(xv[0].z); a[3] = f2bf(xv[0].w);
    a[4] = f2bf(xv[1].x); a[5] = f2bf(xv[1].y); a[6] = f2bf(xv[1].z); a[7] = f2bf(xv[1].w);
    *(s16x8*)&xa[sel][sr * 72 + cg8] = a;
  };

  // prologue: stage k-step 0
  float4 xf[2];
  xf[0] = *(const float4*)(xp);
  xf[1] = *(const float4*)(xp + 4);
  STAGE_W(0, 0);
  WRITE_X(0, xf);

  int cur = 0;
  for (int it = 0; it < 32; ++it) {
    __syncthreads();  // buf[cur] ready: W vmcnt drained + xa writes visible
    if (it + 1 < 32) {
      STAGE_W(cur ^ 1, it + 1);  // async during compute
      const float* xpn = xp + (it + 1) * 64;
      xf[0] = *(const float4*)(xpn);
      xf[1] = *(const float4*)(xpn + 4);
    }

#pragma unroll
    for (int kc = 0; kc < 2; ++kc) {
      const int ko = kc * 32 + quad * 8;
      s16x8 af[2], bfr[3];
#pragma unroll
      for (int mg = 0; mg < 2; ++mg)
        af[mg] = *(const s16x8*)&xa[cur][(wm * 32 + mg * 16 + l15) * 72 + ko];
#pragma unroll
      for (int nt = 0; nt < 3; ++nt) {
        int col = wn * 48 + nt * 16 + l15;
        bfr[nt] = *(const s16x8*)((const char*)&wb[cur][0] + (size_t)col * 128 +
                                  ((kc * 64 + quad * 16) ^ ((col & 7) << 4)));
      }
#pragma unroll
      for (int mg = 0; mg < 2; ++mg)
#pragma unroll
        for (int nt = 0; nt < 3; ++nt)
          acc[mg][nt] = __builtin_amdgcn_mfma_f32_16x16x32_bf16(
              af[mg], bfr[nt], acc[mg][nt], 0, 0, 0);
    }

    if (it + 1 < 32) WRITE_X(cur ^ 1, xf);  // xa[cur^1] readers done pre-barrier
    cur ^= 1;
  }

  const float scale = 0.08838834764831845f;  // 1/sqrt(128), folded into Q
  const int b = row0 >> 12;
  const int s_base = row0 & (S_ - 1);
#pragma unroll
  for (int nt = 0; nt < 3; ++nt) {
    int col = nc0 + wn * 48 + nt * 16 + l15;
    int p = col >> 7;
    int h = col & (H_ - 1);
    if (p == 2) {
      float bsv = bv[h];
#pragma unroll
      for (int mg = 0; mg < 2; ++mg) {
        int s0 = s_base + wm * 32 + mg * 16 + quad * 4;
        s16x4 vv;
#pragma unroll
        for (int r = 0; r < 4; ++r) vv[r] = f2bf(acc[mg][nt][r] + bsv);
        *(s16x4*)&Vt[((size_t)b * H_ + h) * S_ + s0] = vv;
      }
    } else if (p == 0) {
      float bsv = bq[h];
#pragma unroll
      for (int mg = 0; mg < 2; ++mg)
#pragma unroll
        for (int r = 0; r < 4; ++r) {
          int row = row0 + wm * 32 + mg * 16 + quad * 4 + r;
          Q[(size_t)row * H_ + h] = f2bf((acc[mg][nt][r] + bsv) * scale);
        }
    } else {
      float bsv = bk[h];
#pragma unroll
      for (int mg = 0; mg < 2; ++mg)
#pragma unroll
        for (int r = 0; r < 4; ++r) {
          int row = row0 + wm * 32 + mg * 16 + quad * 4 + r;
          K[(size_t)row * H_ + h] = f2bf(acc[mg][nt][r] + bsv);
        }
    }
  }
}

// ---------------------------------------------------------------------------
// Kernel 3: causal flash attention — R13 (unchanged; split-K + 2 blocks/CU).
// ---------------------------------------------------------------------------
__global__ __launch_bounds__(512) void flash_attn(
    const short* __restrict__ Qb, const short* __restrict__ Kb,
    const short* __restrict__ Vtb, float* __restrict__ O0,
    float* __restrict__ O1, float* __restrict__ ML) {
  __shared__ __attribute__((aligned(16))) short KT[2][64 * 128];  // 2x16KB
  __shared__ __attribute__((aligned(16))) short VT[2][128 * 64];  // 2x16KB
  __shared__ float mx[2][8][16];                                  // 1KB
  __shared__ float lx[8][16];                                     // 512B

  const int tid = threadIdx.x;
  const int w = tid >> 6;
  const int lane = tid & 63;
  const int l15 = lane & 15;
  const int quad = lane >> 4;
  const int rg = w & 3;        // row-group: rows 16*rg .. 16*rg+15
  const int kh = w >> 2;       // key-half within tile: keys kh*32 ..
  const int bid = (int)blockIdx.x;
  const int half = bid & 1;    // split-K half
  const int slot = bid >> 1;
  const int b = slot & 3;
  const int T = 63 - (slot >> 2);  // heavy q-tiles first
  const int q0 = T * 64;
  const int nk = T + 1;
  const int hsplit = (nk + 1) >> 1;
  const int i0 = half ? hsplit : 0;
  const int i1 = half ? nk : hsplit;
  const size_t bo = (size_t)b * S_ * H_;
  const short* Kg = Kb + bo;                    // [s][h], 256B rows
  const short* Vg = Vtb + (size_t)b * H_ * S_;  // [h][s], 8192B rows
  const float L2E = 1.4426950408889634f;

  auto STAGE = [&](int sel, int kb) {
    const char* kgp = (const char*)Kg + (size_t)kb * 256;
    const char* vgp = (const char*)Vg + (size_t)kb * 2;
    char* kl = (char*)&KT[sel][0] + (8 * w) * 256;
    char* vl = (char*)&VT[sel][0] + (16 * w) * 128;
#pragma unroll
    for (int j = 0; j < 2; ++j) {
      int krow = 8 * w + 4 * j + (lane >> 4);
      int kcol = ((lane & 15) << 4) ^ ((((lane >> 4) + 4 * j) & 7) << 4);
      gload_lds16(kgp + (size_t)krow * 256 + kcol, kl + j * 1024);
      int vrow = 16 * w + 8 * j + (lane >> 3);
      int vcol = ((lane & 7) << 4) ^ (((lane >> 3) & 7) << 4);
      gload_lds16(vgp + (size_t)vrow * 8192 + vcol, vl + j * 1024);
    }
  };

  s16x8 aq[4];
#pragma unroll
  for (int kt = 0; kt < 4; ++kt)
    aq[kt] = *(const s16x8*)(Qb + bo + (size_t)(q0 + 16 * rg + l15) * H_ +
                             kt * 32 + quad * 8);

  f32x4 oacc[8];
#pragma unroll
  for (int nt = 0; nt < 8; ++nt) oacc[nt] = (f32x4){0.f, 0.f, 0.f, 0.f};
  float m15 = -3.0e38f;
  float mT[4];
  float l15acc = 0.f;
#pragma unroll
  for (int r = 0; r < 4; ++r) mT[r] = -3.0e38f;

  const int swr = (l15 & 7) << 4;
  const int q4 = quad * 4;

  int cur = 0;
  if (i0 < i1) STAGE(0, i0 * 64);
  for (int i = i0; i < i1; ++i) {
    __syncthreads();
    if (i + 1 < i1) STAGE(cur ^ 1, (i + 1) * 64);

    const char* Kl = (const char*)&KT[cur][0];
    const char* Vl = (const char*)&VT[cur][0];

    f32x4 sc[2];
#pragma unroll
    for (int nt = 0; nt < 2; ++nt) {
      f32x4 a = (f32x4){0.f, 0.f, 0.f, 0.f};
      const int krow = kh * 32 + nt * 16 + l15;
#pragma unroll
      for (int kt = 0; kt < 4; ++kt) {
        const s16x8 kf = *(const s16x8*)(Kl + krow * 256 +
                                         ((kt * 64 + quad * 16) ^ swr));
        a = __builtin_amdgcn_mfma_f32_16x16x32_bf16(kf, aq[kt], a, 0, 0, 0);
      }
      sc[nt] = a;
    }

    if (i == nk - 1) {
      const int qrow = 16 * rg + l15;
#pragma unroll
      for (int nt = 0; nt < 2; ++nt)
#pragma unroll
        for (int r = 0; r < 4; ++r)
          if (kh * 32 + nt * 16 + q4 + r > qrow) sc[nt][r] = -3.0e38f;
    }

    float vm = fmaxf(fmaxf(fmaxf(sc[0][0], sc[0][1]), fmaxf(sc[0][2], sc[0][3])),
                     fmaxf(fmaxf(sc[1][0], sc[1][1]), fmaxf(sc[1][2], sc[1][3])));
    vm = fmaxf(vm, __shfl_xor(vm, 16));
    vm = fmaxf(vm, __shfl_xor(vm, 32));
    const int par = i & 1;
    if (lane < 16) mx[par][w][lane] = vm;
    __asm__ volatile("s_waitcnt lgkmcnt(0)" ::: "memory");
    __asm__ volatile("s_barrier" ::: "memory");

    float tile_m = fmaxf(vm, mx[par][w ^ 4][l15]);
    float mn = fmaxf(m15, tile_m);
    float al15 = exp2f((m15 - mn) * L2E);
    m15 = mn;
    float alT[4];
#pragma unroll
    for (int r = 0; r < 4; ++r) {
      float a2 = fmaxf(mx[par][w][q4 + r], mx[par][w ^ 4][q4 + r]);
      float mnT = fmaxf(mT[r], a2);
      alT[r] = exp2f((mT[r] - mnT) * L2E);
      mT[r] = mnT;
    }

    s16x4 ap[2];
    float lpart = 0.f;
#pragma unroll
    for (int nt = 0; nt < 2; ++nt)
#pragma unroll
      for (int r = 0; r < 4; ++r) {
        float pv = exp2f((sc[nt][r] - m15) * L2E);
        lpart += pv;
        ap[nt][r] = f2bf(pv);
      }
    l15acc = l15acc * al15 + lpart;

#pragma unroll
    for (int ht = 0; ht < 8; ++ht)
#pragma unroll
      for (int r = 0; r < 4; ++r) oacc[ht][r] *= alT[r];

#pragma unroll
    for (int ht = 0; ht < 8; ++ht) {
#pragma unroll
      for (int nt = 0; nt < 2; ++nt) {
        const s16x4 vf = *(const s16x4*)(Vl + (ht * 16 + l15) * 128 +
                                         ((kh * 64 + nt * 32 + quad * 8) ^ swr));
        oacc[ht] = mfma16x16x16(ap[nt], vf, oacc[ht]);
      }
    }

    cur ^= 1;
  }

  float lw = l15acc;
  lw += __shfl_xor(lw, 16);
  lw += __shfl_xor(lw, 32);
  if (lane < 16) lx[w][lane] = lw;
  __syncthreads();

  float* Ob = (float*)&KT[0][0];
  if (kh == 1) {
#pragma unroll
    for (int ht = 0; ht < 8; ++ht)
#pragma unroll
      for (int r = 0; r < 4; ++r)
        Ob[rg * 2048 + (q4 + r) * 128 + ht * 16 + l15] = oacc[ht][r];
  }
  __syncthreads();
  if (kh == 0) {
    float* Od = half ? O1 : O0;
    if (l15 == 0) {
#pragma unroll
      for (int r = 0; r < 4; ++r) {
        int row = q0 + 16 * rg + q4 + r;
        float* mlp = ML + ((size_t)half * (B_ * S_) + b * S_ + row) * 2;
        mlp[0] = mT[r];
        mlp[1] = lx[w][q4 + r] + lx[w ^ 4][q4 + r];
      }
    }
#pragma unroll
    for (int ht = 0; ht < 8; ++ht)
#pragma unroll
      for (int r = 0; r < 4; ++r) {
        float o = oacc[ht][r] + Ob[rg * 2048 + (q4 + r) * 128 + ht * 16 + l15];
        Od[bo + (size_t)(q0 + 16 * rg + q4 + r) * H_ + ht * 16 + l15] = o;
      }
  }
}

// ---------------------------------------------------------------------------
// Kernel 4: merge the two split-K halves (unchanged).
// ---------------------------------------------------------------------------
__global__ __launch_bounds__(256) void merge_halves(
    float* __restrict__ O0, const float* __restrict__ O1,
    const float* __restrict__ ML) {
  const float L2E = 1.4426950408889634f;
  const int total = B_ * S_ * H_;
  int idx = (int)blockIdx.x * 256 + (int)threadIdx.x;
  for (; idx < total; idx += (int)gridDim.x * 256) {
    int brow = idx >> 7;  // b*S + s
    float m1 = ML[(size_t)brow * 2];
    float l1 = ML[(size_t)brow * 2 + 1];
    float m2 = ML[((size_t)(B_ * S_) + brow) * 2];
    float l2 = ML[((size_t)(B_ * S_) + brow) * 2 + 1];
    float M = fmaxf(m1, m2);
    float e1 = exp2f((m1 - M) * L2E);
    float e2 = exp2f((m2 - M) * L2E);
    float denom = e1 * l1 + e2 * l2;
    O0[idx] = (e1 * O0[idx] + e2 * O1[idx]) / denom;
  }
}

// ---------------------------------------------------------------------------
extern "C" void kernel_launch(void* const* d_in, const int* in_sizes, int n_in,
                              void* d_out, int out_size, void* d_ws, size_t ws_size,
                              hipStream_t stream) {
  const float* x  = (const float*)d_in[0];
  const float* Wq = (const float*)d_in[1];
  const float* bq = (const float*)d_in[2];
  const float* Wk = (const float*)d_in[3];
  const float* bk = (const float*)d_in[4];
  const float* Wv = (const float*)d_in[5];
  const float* bv = (const float*)d_in[6];

  // ws: Wt(1.5MB) | Q | K | Vt (4.2MB each, bf16) | O1 (8.4MB f32) | ML (256KB)
  short* Wt = (short*)d_ws;
  short* Q  = Wt + (size_t)384 * E_;
  short* K  = Q + (size_t)B_ * S_ * H_;
  short* Vt = K + (size_t)B_ * S_ * H_;
  float* O1 = (float*)(Vt + (size_t)B_ * S_ * H_);
  float* ML = O1 + (size_t)B_ * S_ * H_;
  float* out = (float*)d_out;

  hipLaunchKernelGGL(prep_weights, dim3(64 * 4, 3), dim3(256), 0, stream,
                     Wq, Wk, Wv, Wt);
  // 512 blocks = 256 row-tiles (64 rows) x 2 N-halves; 512 thr = 8 waves,
  // 2 blocks/CU -> 16 waves/CU (4/SIMD, was 2/SIMD)
  hipLaunchKernelGGL(qkv_gemm, dim3((B_ * S_) / 64 * 2), dim3(512), 0, stream,
                     x, Wt, bq, bk, bv, Q, K, Vt);
  // 512 blocks = 64 q-tiles x 4 batches x 2 split-K halves, 2 blocks/CU
  hipLaunchKernelGGL(flash_attn, dim3(64 * B_ * 2), dim3(512), 0, stream,
                     Q, K, Vt, out, O1, ML);
  hipLaunchKernelGGL(merge_halves, dim3(2048), dim3(256), 0, stream,
                     out, O1, ML);
}

// Round 10
// 292.691 us; speedup vs baseline: 1.1079x; 1.0542x over previous
//
#include <hip/hip_runtime.h>

#define B_ 4
#define S_ 4096
#define E_ 2048
#define H_ 128

using f32x4 = __attribute__((ext_vector_type(4))) float;
using s16x8 = __attribute__((ext_vector_type(8))) short;
using s16x4 = __attribute__((ext_vector_type(4))) short;

// fp32 -> bf16 bits, round-to-nearest-even
__device__ __forceinline__ short f2bf(float f) {
  unsigned u = __float_as_uint(f);
  u += 0x7FFFu + ((u >> 16) & 1u);
  return (short)(u >> 16);
}

// async global(16B/lane, per-lane addr) -> LDS (wave-uniform base + lane*16)
__device__ __forceinline__ void gload_lds16(const void* g, void* l) {
  __builtin_amdgcn_global_load_lds(
      (const __attribute__((address_space(1))) void*)g,
      (__attribute__((address_space(3))) void*)l, 16, 0, 0);
}

// K=16 bf16 MFMA: D(16q x 16h) = A(16q x 16k) * B(16k x 16h) + C
__device__ __forceinline__ f32x4 mfma16x16x16(s16x4 a, s16x4 b, f32x4 c) {
#if __has_builtin(__builtin_amdgcn_mfma_f32_16x16x16bf16_1k)
  return __builtin_amdgcn_mfma_f32_16x16x16bf16_1k(a, b, c, 0, 0, 0);
#elif __has_builtin(__builtin_amdgcn_mfma_f32_16x16x16_bf16)
  return __builtin_amdgcn_mfma_f32_16x16x16_bf16(a, b, c, 0, 0, 0);
#else
  f32x4 d;
  asm("v_mfma_f32_16x16x16_bf16 %0, %1, %2, %3"
      : "=v"(d) : "v"(a), "v"(b), "v"(c));
  return d;
#endif
}

// ---------------------------------------------------------------------------
// Kernel 1: W (E x H fp32) x3 -> Wt K-panel layout [kb][col][64k], bf16.
// ---------------------------------------------------------------------------
__global__ __launch_bounds__(256) void prep_weights(
    const float* __restrict__ Wq, const float* __restrict__ Wk,
    const float* __restrict__ Wv, short* __restrict__ Wt) {
  __shared__ float T[32 * 33];
  int p = blockIdx.y;
  const float* W = (p == 0) ? Wq : ((p == 1) ? Wk : Wv);
  int e0 = (blockIdx.x & 63) * 32;
  int h0 = (blockIdx.x >> 6) * 32;
  int r = threadIdx.x >> 5;
  int c = threadIdx.x & 31;
#pragma unroll
  for (int i = 0; i < 4; ++i) {
    int e = r + 8 * i;
    T[c * 33 + e] = W[(size_t)(e0 + e) * H_ + h0 + c];
  }
  __syncthreads();
  const int kb = e0 >> 6;
  const int kq = e0 & 32;
#pragma unroll
  for (int i = 0; i < 4; ++i) {
    int h = r + 8 * i;
    int col = p * H_ + h0 + h;
    Wt[((size_t)kb * 384 + col) * 64 + kq + c] = f2bf(T[h * 33 + c]);
  }
}

// ---------------------------------------------------------------------------
// Kernel 2: fused QKV projection GEMM — R15 (unchanged, measured 87.4 us).
// ---------------------------------------------------------------------------
__global__ __launch_bounds__(512) void qkv_gemm(
    const float* __restrict__ x, const short* __restrict__ Wt,
    const float* __restrict__ bq, const float* __restrict__ bk,
    const float* __restrict__ bv,
    short* __restrict__ Q, short* __restrict__ K, short* __restrict__ Vt) {
  __shared__ __attribute__((aligned(16))) short xa[2][64 * 72];   // 18.4 KB
  __shared__ __attribute__((aligned(16))) short wb[2][192 * 64];  // 48 KB

  const int tid = threadIdx.x;
  const int wave = tid >> 6;
  const int lane = tid & 63;
  const int l15 = lane & 15;
  const int quad = lane >> 4;
  const int wm = wave >> 2;   // row half: rows wm*32 .. wm*32+31
  const int wn = wave & 3;    // col quarter: cols wn*48 .. wn*48+47
  const int bid = (int)blockIdx.x;
  const int row0 = (bid >> 1) * 64;
  const int nc0 = (bid & 1) * 192;

  const int sr = tid >> 3;
  const int cg8 = (tid & 7) * 8;
  const float* xp = x + (size_t)(row0 + sr) * E_ + cg8;

  const int wl8 = lane >> 3;
  const int l7 = lane & 7;

  f32x4 acc[2][3];
#pragma unroll
  for (int mg = 0; mg < 2; ++mg)
#pragma unroll
    for (int nt = 0; nt < 3; ++nt) acc[mg][nt] = (f32x4){0.f, 0.f, 0.f, 0.f};

  auto STAGE_W = [&](int sel, int it) {
    const char* pan = (const char*)(Wt + ((size_t)it * 384 + nc0) * 64);
    char* dst = (char*)&wb[sel][0] + (size_t)(wave * 24) * 128;
#pragma unroll
    for (int j2 = 0; j2 < 3; ++j2) {
      int col = wave * 24 + j2 * 8 + wl8;
      const char* src = pan + (size_t)col * 128 + ((l7 * 16) ^ ((col & 7) << 4));
      gload_lds16(src, dst + j2 * 1024);
    }
  };
  auto WRITE_X = [&](int sel, const float4* xv) {
    s16x8 a;
    a[0] = f2bf(xv[0].x); a[1] = f2bf(xv[0].y); a[2] = f2bf(xv[0].z); a[3] = f2bf(xv[0].w);
    a[4] = f2bf(xv[1].x); a[5] = f2bf(xv[1].y); a[6] = f2bf(xv[1].z); a[7] = f2bf(xv[1].w);
    *(s16x8*)&xa[sel][sr * 72 + cg8] = a;
  };

  float4 xf[2];
  xf[0] = *(const float4*)(xp);
  xf[1] = *(const float4*)(xp + 4);
  STAGE_W(0, 0);
  WRITE_X(0, xf);

  int cur = 0;
  for (int it = 0; it < 32; ++it) {
    __syncthreads();
    if (it + 1 < 32) {
      STAGE_W(cur ^ 1, it + 1);
      const float* xpn = xp + (it + 1) * 64;
      xf[0] = *(const float4*)(xpn);
      xf[1] = *(const float4*)(xpn + 4);
    }

#pragma unroll
    for (int kc = 0; kc < 2; ++kc) {
      const int ko = kc * 32 + quad * 8;
      s16x8 af[2], bfr[3];
#pragma unroll
      for (int mg = 0; mg < 2; ++mg)
        af[mg] = *(const s16x8*)&xa[cur][(wm * 32 + mg * 16 + l15) * 72 + ko];
#pragma unroll
      for (int nt = 0; nt < 3; ++nt) {
        int col = wn * 48 + nt * 16 + l15;
        bfr[nt] = *(const s16x8*)((const char*)&wb[cur][0] + (size_t)col * 128 +
                                  ((kc * 64 + quad * 16) ^ ((col & 7) << 4)));
      }
#pragma unroll
      for (int mg = 0; mg < 2; ++mg)
#pragma unroll
        for (int nt = 0; nt < 3; ++nt)
          acc[mg][nt] = __builtin_amdgcn_mfma_f32_16x16x32_bf16(
              af[mg], bfr[nt], acc[mg][nt], 0, 0, 0);
    }

    if (it + 1 < 32) WRITE_X(cur ^ 1, xf);
    cur ^= 1;
  }

  const float scale = 0.08838834764831845f;  // 1/sqrt(128), folded into Q
  const int b = row0 >> 12;
  const int s_base = row0 & (S_ - 1);
#pragma unroll
  for (int nt = 0; nt < 3; ++nt) {
    int col = nc0 + wn * 48 + nt * 16 + l15;
    int p = col >> 7;
    int h = col & (H_ - 1);
    if (p == 2) {
      float bsv = bv[h];
#pragma unroll
      for (int mg = 0; mg < 2; ++mg) {
        int s0 = s_base + wm * 32 + mg * 16 + quad * 4;
        s16x4 vv;
#pragma unroll
        for (int r = 0; r < 4; ++r) vv[r] = f2bf(acc[mg][nt][r] + bsv);
        *(s16x4*)&Vt[((size_t)b * H_ + h) * S_ + s0] = vv;
      }
    } else if (p == 0) {
      float bsv = bq[h];
#pragma unroll
      for (int mg = 0; mg < 2; ++mg)
#pragma unroll
        for (int r = 0; r < 4; ++r) {
          int row = row0 + wm * 32 + mg * 16 + quad * 4 + r;
          Q[(size_t)row * H_ + h] = f2bf((acc[mg][nt][r] + bsv) * scale);
        }
    } else {
      float bsv = bk[h];
#pragma unroll
      for (int mg = 0; mg < 2; ++mg)
#pragma unroll
        for (int r = 0; r < 4; ++r) {
          int row = row0 + wm * 32 + mg * 16 + quad * 4 + r;
          K[(size_t)row * H_ + h] = f2bf(acc[mg][nt][r] + bsv);
        }
    }
  }
}

// ---------------------------------------------------------------------------
// Kernel 3: causal flash attention — R16.
// R15 analysis: flash (and qkv) sit at ~6400cy wall per barrier-iter per CU
// vs ~2000cy pipe work — the measured 2-phase structural stall (stage +
// vmcnt + barrier). Every win so far came from cross-block TLP covering
// that stall (R13: 2 blocks/CU; R15: 8 waves). One more dose for flash:
//  - SINGLE-buffer K/V staging: LDS 66.5 -> 34.3 KB. KT/VT share one 32KB
//    block (SB), reused as the f32 O-merge buffer in the epilogue.
//  - 3-way SPLIT-K: block sp of (b,T) covers key-tiles [nk*sp/3,
//    nk*(sp+1)/3). Grid 768 = 3 blocks/CU, 24 waves/CU (was 16). Max block
//    22 iters (was 32); per-CU mean ~32.5 unchanged.
//  - Loop: barrier(WAR) -> STAGE -> barrier(staged) -> compute. In-block
//    prefetch traded for cross-block overlap (m114 wave-level overlap).
// Inner compute (swapped QK^T, in-reg P, kh-split) byte-identical to R13.
// ---------------------------------------------------------------------------
__global__ __launch_bounds__(512) void flash_attn(
    const short* __restrict__ Qb, const short* __restrict__ Kb,
    const short* __restrict__ Vtb, float* __restrict__ O0,
    float* __restrict__ O1, float* __restrict__ O2, float* __restrict__ ML) {
  // KT [64][128] + VT [128][64] share SB; epilogue reuses SB as 32KB f32 Ob.
  __shared__ __attribute__((aligned(16))) short SB[64 * 128 + 128 * 64];
  __shared__ float mx[2][8][16];  // 1 KB
  __shared__ float lx[8][16];     // 512 B
  short* KTb = SB;
  short* VTb = SB + 64 * 128;

  const int tid = threadIdx.x;
  const int w = tid >> 6;
  const int lane = tid & 63;
  const int l15 = lane & 15;
  const int quad = lane >> 4;
  const int rg = w & 3;        // row-group: rows 16*rg .. 16*rg+15
  const int kh = w >> 2;       // key-half within tile: keys kh*32 ..
  const int bid = (int)blockIdx.x;
  const int slot = bid / 3;
  const int sp = bid - slot * 3;   // split index 0..2
  const int b = slot & 3;
  const int T = 63 - (slot >> 2);  // heavy q-tiles first
  const int q0 = T * 64;
  const int nk = T + 1;
  const int i0 = (nk * sp) / 3;
  const int i1 = (nk * (sp + 1)) / 3;
  const size_t bo = (size_t)b * S_ * H_;
  const short* Kg = Kb + bo;                    // [s][h], 256B rows
  const short* Vg = Vtb + (size_t)b * H_ * S_;  // [h][s], 8192B rows
  const float L2E = 1.4426950408889634f;

  auto STAGE = [&](int kb) {
    const char* kgp = (const char*)Kg + (size_t)kb * 256;
    const char* vgp = (const char*)Vg + (size_t)kb * 2;
    char* kl = (char*)KTb + (8 * w) * 256;
    char* vl = (char*)VTb + (16 * w) * 128;
#pragma unroll
    for (int j = 0; j < 2; ++j) {
      int krow = 8 * w + 4 * j + (lane >> 4);
      int kcol = ((lane & 15) << 4) ^ ((((lane >> 4) + 4 * j) & 7) << 4);
      gload_lds16(kgp + (size_t)krow * 256 + kcol, kl + j * 1024);
      int vrow = 16 * w + 8 * j + (lane >> 3);
      int vcol = ((lane & 7) << 4) ^ (((lane >> 3) & 7) << 4);
      gload_lds16(vgp + (size_t)vrow * 8192 + vcol, vl + j * 1024);
    }
  };

  s16x8 aq[4];
#pragma unroll
  for (int kt = 0; kt < 4; ++kt)
    aq[kt] = *(const s16x8*)(Qb + bo + (size_t)(q0 + 16 * rg + l15) * H_ +
                             kt * 32 + quad * 8);

  f32x4 oacc[8];
#pragma unroll
  for (int nt = 0; nt < 8; ++nt) oacc[nt] = (f32x4){0.f, 0.f, 0.f, 0.f};
  float m15 = -3.0e38f;
  float mT[4];
  float l15acc = 0.f;
#pragma unroll
  for (int r = 0; r < 4; ++r) mT[r] = -3.0e38f;

  const int swr = (l15 & 7) << 4;
  const int q4 = quad * 4;

  for (int i = i0; i < i1; ++i) {
    __syncthreads();  // WAR: all waves done reading SB (previous iteration)
    STAGE(i * 64);
    __syncthreads();  // staged: per-wave vmcnt(0) drain -> LDS writes visible

    f32x4 sc[2];
#pragma unroll
    for (int nt = 0; nt < 2; ++nt) {
      f32x4 a = (f32x4){0.f, 0.f, 0.f, 0.f};
      const int krow = kh * 32 + nt * 16 + l15;
#pragma unroll
      for (int kt = 0; kt < 4; ++kt) {
        const s16x8 kf = *(const s16x8*)((const char*)KTb + krow * 256 +
                                         ((kt * 64 + quad * 16) ^ swr));
        a = __builtin_amdgcn_mfma_f32_16x16x32_bf16(kf, aq[kt], a, 0, 0, 0);
      }
      sc[nt] = a;
    }

    if (i == nk - 1) {  // diagonal tile: causal mask
      const int qrow = 16 * rg + l15;
#pragma unroll
      for (int nt = 0; nt < 2; ++nt)
#pragma unroll
        for (int r = 0; r < 4; ++r)
          if (kh * 32 + nt * 16 + q4 + r > qrow) sc[nt][r] = -3.0e38f;
    }

    float vm = fmaxf(fmaxf(fmaxf(sc[0][0], sc[0][1]), fmaxf(sc[0][2], sc[0][3])),
                     fmaxf(fmaxf(sc[1][0], sc[1][1]), fmaxf(sc[1][2], sc[1][3])));
    vm = fmaxf(vm, __shfl_xor(vm, 16));
    vm = fmaxf(vm, __shfl_xor(vm, 32));
    const int par = i & 1;
    if (lane < 16) mx[par][w][lane] = vm;
    __asm__ volatile("s_waitcnt lgkmcnt(0)" ::: "memory");
    __asm__ volatile("s_barrier" ::: "memory");  // raw: no vmcnt drain

    float tile_m = fmaxf(vm, mx[par][w ^ 4][l15]);
    float mn = fmaxf(m15, tile_m);
    float al15 = exp2f((m15 - mn) * L2E);
    m15 = mn;
    float alT[4];
#pragma unroll
    for (int r = 0; r < 4; ++r) {
      float a2 = fmaxf(mx[par][w][q4 + r], mx[par][w ^ 4][q4 + r]);
      float mnT = fmaxf(mT[r], a2);
      alT[r] = exp2f((mT[r] - mnT) * L2E);
      mT[r] = mnT;
    }

    s16x4 ap[2];
    float lpart = 0.f;
#pragma unroll
    for (int nt = 0; nt < 2; ++nt)
#pragma unroll
      for (int r = 0; r < 4; ++r) {
        float pv = exp2f((sc[nt][r] - m15) * L2E);
        lpart += pv;
        ap[nt][r] = f2bf(pv);
      }
    l15acc = l15acc * al15 + lpart;

#pragma unroll
    for (int ht = 0; ht < 8; ++ht)
#pragma unroll
      for (int r = 0; r < 4; ++r) oacc[ht][r] *= alT[r];

#pragma unroll
    for (int ht = 0; ht < 8; ++ht) {
#pragma unroll
      for (int nt = 0; nt < 2; ++nt) {
        const s16x4 vf = *(const s16x4*)((const char*)VTb +
                                         (ht * 16 + l15) * 128 +
                                         ((kh * 64 + nt * 32 + quad * 8) ^ swr));
        oacc[ht] = mfma16x16x16(ap[nt], vf, oacc[ht]);
      }
    }
  }

  // ---- epilogue: l reduce, kh-merge via SB (KT/VT dead), partial write ----
  float lw = l15acc;
  lw += __shfl_xor(lw, 16);
  lw += __shfl_xor(lw, 32);
  if (lane < 16) lx[w][lane] = lw;
  __syncthreads();  // all waves done with SB; lx visible

  float* Ob = (float*)SB;  // 32KB: [rg][16 rows][128 cols]
  if (kh == 1) {
#pragma unroll
    for (int ht = 0; ht < 8; ++ht)
#pragma unroll
      for (int r = 0; r < 4; ++r)
        Ob[rg * 2048 + (q4 + r) * 128 + ht * 16 + l15] = oacc[ht][r];
  }
  __syncthreads();
  if (kh == 0) {
    float* Od = (sp == 0) ? O0 : ((sp == 1) ? O1 : O2);
    if (l15 == 0) {
#pragma unroll
      for (int r = 0; r < 4; ++r) {
        int row = q0 + 16 * rg + q4 + r;
        float* mlp = ML + ((size_t)sp * (B_ * S_) + b * S_ + row) * 2;
        mlp[0] = mT[r];
        mlp[1] = lx[w][q4 + r] + lx[w ^ 4][q4 + r];
      }
    }
#pragma unroll
    for (int ht = 0; ht < 8; ++ht)
#pragma unroll
      for (int r = 0; r < 4; ++r) {
        float o = oacc[ht][r] + Ob[rg * 2048 + (q4 + r) * 128 + ht * 16 + l15];
        Od[bo + (size_t)(q0 + 16 * rg + q4 + r) * H_ + ht * 16 + l15] = o;
      }
  }
}

// ---------------------------------------------------------------------------
// Kernel 4: merge the three split-K partials.
// out = sum_i(e_i*O_i) / sum_i(e_i*l_i); empty split (m=-3e38,l=0,O=0) -> e=0.
// ---------------------------------------------------------------------------
__global__ __launch_bounds__(256) void merge_halves(
    float* __restrict__ O0, const float* __restrict__ O1,
    const float* __restrict__ O2, const float* __restrict__ ML) {
  const float L2E = 1.4426950408889634f;
  const int total = B_ * S_ * H_;
  int idx = (int)blockIdx.x * 256 + (int)threadIdx.x;
  for (; idx < total; idx += (int)gridDim.x * 256) {
    int brow = idx >> 7;  // b*S + s
    float m0 = ML[(size_t)brow * 2];
    float l0 = ML[(size_t)brow * 2 + 1];
    float m1 = ML[((size_t)(B_ * S_) + brow) * 2];
    float l1 = ML[((size_t)(B_ * S_) + brow) * 2 + 1];
    float m2 = ML[((size_t)(2 * B_ * S_) + brow) * 2];
    float l2 = ML[((size_t)(2 * B_ * S_) + brow) * 2 + 1];
    float M = fmaxf(fmaxf(m0, m1), m2);
    float e0 = exp2f((m0 - M) * L2E);
    float e1 = exp2f((m1 - M) * L2E);
    float e2 = exp2f((m2 - M) * L2E);
    float denom = e0 * l0 + e1 * l1 + e2 * l2;
    O0[idx] = (e0 * O0[idx] + e1 * O1[idx] + e2 * O2[idx]) / denom;
  }
}

// ---------------------------------------------------------------------------
extern "C" void kernel_launch(void* const* d_in, const int* in_sizes, int n_in,
                              void* d_out, int out_size, void* d_ws, size_t ws_size,
                              hipStream_t stream) {
  const float* x  = (const float*)d_in[0];
  const float* Wq = (const float*)d_in[1];
  const float* bq = (const float*)d_in[2];
  const float* Wk = (const float*)d_in[3];
  const float* bk = (const float*)d_in[4];
  const float* Wv = (const float*)d_in[5];
  const float* bv = (const float*)d_in[6];

  // ws: Wt(1.6MB) | Q|K|Vt (4.2MB ea bf16) | O1,O2 (8.4MB ea f32) | ML(0.4MB)
  // total ~31.4 MB
  short* Wt = (short*)d_ws;
  short* Q  = Wt + (size_t)384 * E_;
  short* K  = Q + (size_t)B_ * S_ * H_;
  short* Vt = K + (size_t)B_ * S_ * H_;
  float* O1 = (float*)(Vt + (size_t)B_ * S_ * H_);
  float* O2 = O1 + (size_t)B_ * S_ * H_;
  float* ML = O2 + (size_t)B_ * S_ * H_;
  float* out = (float*)d_out;

  hipLaunchKernelGGL(prep_weights, dim3(64 * 4, 3), dim3(256), 0, stream,
                     Wq, Wk, Wv, Wt);
  hipLaunchKernelGGL(qkv_gemm, dim3((B_ * S_) / 64 * 2), dim3(512), 0, stream,
                     x, Wt, bq, bk, bv, Q, K, Vt);
  // 768 blocks = 64 q-tiles x 4 batches x 3 split-K parts, 3 blocks/CU
  hipLaunchKernelGGL(flash_attn, dim3(64 * B_ * 3), dim3(512), 0, stream,
                     Q, K, Vt, out, O1, O2, ML);
  hipLaunchKernelGGL(merge_halves, dim3(2048), dim3(256), 0, stream,
                     out, O1, O2, ML);
}